// Round 1
// 74.838 us; speedup vs baseline: 1.0204x; 1.0204x over previous
//
#include <hip/hip_runtime.h>

// PIQuantumDQN: 4-qubit, 5-layer re-uploading circuit, B=524288 samples.
// R12: back to TWO samples per thread (one v2f-packed state re[16]/im[16]
// = 64 VGPRs). R11's 4-sample variant pushed total pressure past what the
// allocator would give arch VGPRs (rocprof: 68 arch VGPR => state lived in
// AGPRs, v_accvgpr_read/write around every gate op => latency-bound at 20%
// VALUBusy, 19% occupancy). Here: ~120 VGPR total, __launch_bounds__(256,4)
// caps at 128, grid = 1024 blocks = 4 blocks/CU = 16 waves/CU.
// Gate forms (R10): RY 3-shear (6 pk/pair), RX tangent (4 pk/pair, uniform
// cos folded into Wu via S^2). CNOTs are register renames.
// wire q (0 = MSB) <-> bit (3-q) of the flat index, so mask(q) = 8 >> q.

typedef float v2f __attribute__((ext_vector_type(2)));

__device__ __forceinline__ v2f splat(float x) { return (v2f){x, x}; }

__device__ __forceinline__ float rfl(float v) {
    return __uint_as_float(__builtin_amdgcn_readfirstlane(__float_as_uint(v)));
}

// RY via 3 shears on both planes: x-=t*y; y+=s*x; x-=t*y
template<int MASK>
__device__ __forceinline__ void apply_ry_sh(v2f (&re)[16], v2f (&im)[16],
                                            v2f t, v2f s) {
#pragma unroll
    for (int i0 = 0; i0 < 16; ++i0) {
        if (i0 & MASK) continue;
        const int i1 = i0 | MASK;
        v2f x, y;
        x = re[i0]; y = re[i1];
        x = x - t * y; y = y + s * x; x = x - t * y;
        re[i0] = x; re[i1] = y;
        x = im[i0]; y = im[i1];
        x = x - t * y; y = y + s * x; x = x - t * y;
        im[i0] = x; im[i1] = y;
    }
}

// RX tangent form; true output = cos(w/2) * (this output), folded into Wu.
template<int MASK>
__device__ __forceinline__ void apply_rx_t(v2f (&re)[16], v2f (&im)[16], v2f t) {
#pragma unroll
    for (int i0 = 0; i0 < 16; ++i0) {
        if (i0 & MASK) continue;
        const int i1 = i0 | MASK;
        v2f r0 = re[i0], r1 = re[i1];
        v2f m0 = im[i0], m1 = im[i1];
        re[i0] = t * m1 + r0;
        im[i0] = m0 - t * r1;
        re[i1] = t * m0 + r1;
        im[i1] = m1 - t * r0;
    }
}

template<int CMASK, int TMASK>
__device__ __forceinline__ void apply_cnot(v2f (&re)[16], v2f (&im)[16]) {
#pragma unroll
    for (int i = 0; i < 16; ++i) {
        if ((i & CMASK) && !(i & TMASK)) {
            const int j = i | TMASK;
            v2f tr = re[i]; re[i] = re[j]; re[j] = tr;
            v2f ti = im[i]; im[i] = im[j]; im[j] = ti;
        }
    }
}

__global__ __launch_bounds__(256, 4) void qdqn_kernel(
    const float* __restrict__ x,        // (B,4) fp32
    const float* __restrict__ weights,  // (5,4) fp32
    const float* __restrict__ Wm,       // (2,4) fp32
    const float* __restrict__ bv,       // (2,)  fp32
    float4* __restrict__ out,           // (B/2,4): two float2 outputs per entry
    int Bh)                             // B/2 threads
{
    const int t = blockIdx.x * blockDim.x + threadIdx.x;
    if (t >= Bh) return;

    // ---- issue the x loads first so HBM latency overlaps the uniform trig ----
    const float4 x0 = ((const float4*)x)[2 * t + 0];
    const float4 x1 = ((const float4*)x)[2 * t + 1];

    // ---- uniforms: tan(w/2) per gate + accumulated scale S = prod cos(w/2) ----
    float tw[20];
    float S = 1.0f;
    const float INV_4PI = 0.07957747154594767f;   // w/2 rad = w*(1/4pi) rev
#pragma unroll
    for (int k = 0; k < 20; ++k) {
        float rev = weights[k] * INV_4PI;         // uniform -> scalar load
        float c = __builtin_amdgcn_cosf(rev);
        float s = __builtin_amdgcn_sinf(rev);
        tw[k] = rfl(s * __builtin_amdgcn_rcpf(c));
        S *= c;
    }
    S = rfl(S);
    const float S2 = S * S;                       // probs scale by S^2
    float Wu[8];
#pragma unroll
    for (int k = 0; k < 8; ++k) Wu[k] = rfl(Wm[k] * S2);   // fold scale here
    const float b0u = rfl(bv[0]);
    const float b1u = rfl(bv[1]);

    // ---- pack two consecutive samples into one v2f stream ----
    // RY angle phi = xn*pi/2: rev = xn*0.25, |rev|<=0.25.
    // rc=cos(phi)>=0, rs=sin(phi), ryt=tan(phi/2)=rs/(1+rc), |ryt|<=1.
    const float inv_bounds4[4] = { 0.25f / 4.8f, 0.25f / 4.0f, 0.25f / 0.418f, 0.25f / 4.0f };
    const v2f xv[4] = {
        (v2f){x0.x, x1.x}, (v2f){x0.y, x1.y}, (v2f){x0.z, x1.z}, (v2f){x0.w, x1.w}
    };
    v2f rc[4], rs[4], ryt[4];
#pragma unroll
    for (int q = 0; q < 4; ++q) {
        v2f rev = xv[q] * splat(inv_bounds4[q]);
        float ra = fminf(fmaxf(rev.x, -0.25f), 0.25f);
        float rb = fminf(fmaxf(rev.y, -0.25f), 0.25f);
        float sa = __builtin_amdgcn_sinf(ra), ca = __builtin_amdgcn_cosf(ra);
        float sb = __builtin_amdgcn_sinf(rb), cb = __builtin_amdgcn_cosf(rb);
        rs[q] = (v2f){ sa, sb };
        rc[q] = (v2f){ ca, cb };
        ryt[q] = (v2f){ sa * __builtin_amdgcn_rcpf(1.0f + ca),
                        sb * __builtin_amdgcn_rcpf(1.0f + cb) };
    }

    // ---- layer 0 (separable until first CNOT), RX part in tangent form ----
    // (1/cw)*RX(w)RY(a)|0> = (alpha,beta): alpha=(ca,-t*sa), beta=(sa,-t*ca)
    v2f re[16], im[16];
    {
        v2f ar[4], ai[4], br[4], bi[4];
#pragma unroll
        for (int q = 0; q < 4; ++q) {
            v2f tq = splat(tw[q]);
            ar[q] = rc[q];
            ai[q] = -(tq * rs[q]);
            br[q] = rs[q];
            bi[q] = -(tq * rc[q]);
        }
        v2f t2r[4], t2i[4];
#pragma unroll
        for (int i = 0; i < 4; ++i) {
            v2f xr = (i & 2) ? br[0] : ar[0], xi = (i & 2) ? bi[0] : ai[0];
            v2f yr = (i & 1) ? br[1] : ar[1], yi = (i & 1) ? bi[1] : ai[1];
            t2r[i] = xr * yr - xi * yi;
            t2i[i] = xr * yi + xi * yr;
        }
        v2f t3r[8], t3i[8];
#pragma unroll
        for (int i = 0; i < 8; ++i) {
            v2f xr = t2r[i >> 1], xi = t2i[i >> 1];
            v2f yr = (i & 1) ? br[2] : ar[2], yi = (i & 1) ? bi[2] : ai[2];
            t3r[i] = xr * yr - xi * yi;
            t3i[i] = xr * yi + xi * yr;
        }
#pragma unroll
        for (int i = 0; i < 16; ++i) {
            v2f xr = t3r[i >> 1], xi = t3i[i >> 1];
            v2f yr = (i & 1) ? br[3] : ar[3], yi = (i & 1) ? bi[3] : ai[3];
            re[i] = xr * yr - xi * yi;
            im[i] = xr * yi + xi * yr;
        }
    }
    apply_cnot<8, 4>(re, im);
    apply_cnot<4, 2>(re, im);
    apply_cnot<2, 1>(re, im);
    apply_cnot<1, 8>(re, im);

    // ---- layers 1..4: shear RY (6/pair), tangent RX (4/pair), free CNOTs ----
#pragma unroll
    for (int l = 1; l < 5; ++l) {
        apply_ry_sh<8>(re, im, ryt[0], rs[0]);
        apply_ry_sh<4>(re, im, ryt[1], rs[1]);
        apply_ry_sh<2>(re, im, ryt[2], rs[2]);
        apply_ry_sh<1>(re, im, ryt[3], rs[3]);
        apply_rx_t<8>(re, im, splat(tw[l * 4 + 0]));
        apply_rx_t<4>(re, im, splat(tw[l * 4 + 1]));
        apply_rx_t<2>(re, im, splat(tw[l * 4 + 2]));
        apply_rx_t<1>(re, im, splat(tw[l * 4 + 3]));
        apply_cnot<8, 4>(re, im);
        apply_cnot<4, 2>(re, im);
        apply_cnot<2, 1>(re, im);
        apply_cnot<1, 8>(re, im);
    }

    // ---- probs -> <Z_q> sign tree -> linear layer (scale folded in Wu) ----
    v2f p[16];
#pragma unroll
    for (int i = 0; i < 16; ++i) p[i] = re[i] * re[i] + im[i] * im[i];
    v2f tt[8];
#pragma unroll
    for (int i = 0; i < 8; ++i) tt[i] = p[2 * i] + p[2 * i + 1];
    v2f u[4];
#pragma unroll
    for (int i = 0; i < 4; ++i) u[i] = tt[2 * i] + tt[2 * i + 1];
    const v2f z0 = (u[0] + u[1]) - (u[2] + u[3]);           // wire 0 (bit 3)
    const v2f z1 = (u[0] - u[1]) + (u[2] - u[3]);           // wire 1 (bit 2)
    const v2f z2 = (tt[0] - tt[1]) + (tt[2] - tt[3])
                 + (tt[4] - tt[5]) + (tt[6] - tt[7]);       // wire 2 (bit 1)
    const v2f z3 = ((p[0] - p[1]) + (p[2] - p[3]))
                 + ((p[4] - p[5]) + (p[6] - p[7]))
                 + ((p[8] - p[9]) + (p[10] - p[11]))
                 + ((p[12] - p[13]) + (p[14] - p[15]));     // wire 3 (bit 0)

    v2f o0 = splat(b0u), o1 = splat(b1u);
    o0 = splat(Wu[0]) * z0 + o0; o0 = splat(Wu[1]) * z1 + o0;
    o0 = splat(Wu[2]) * z2 + o0; o0 = splat(Wu[3]) * z3 + o0;
    o1 = splat(Wu[4]) * z0 + o1; o1 = splat(Wu[5]) * z1 + o1;
    o1 = splat(Wu[6]) * z2 + o1; o1 = splat(Wu[7]) * z3 + o1;

    out[t] = make_float4(o0.x, o1.x, o0.y, o1.y);
}

extern "C" void kernel_launch(void* const* d_in, const int* in_sizes, int n_in,
                              void* d_out, int out_size, void* d_ws, size_t ws_size,
                              hipStream_t stream) {
    const float* x  = (const float*)d_in[0];
    const float* w  = (const float*)d_in[1];
    const float* Wm = (const float*)d_in[2];
    const float* bv = (const float*)d_in[3];
    float4* out = (float4*)d_out;

    const int B  = in_sizes[0] / 4;
    const int Bh = B / 2;                       // B divisible by 2 (524288)
    dim3 grid((Bh + 255) / 256), block(256);
    qdqn_kernel<<<grid, block, 0, stream>>>(x, w, Wm, bv, out, Bh);
}

// Round 2
// 74.819 us; speedup vs baseline: 1.0206x; 1.0003x over previous
//
#include <hip/hip_runtime.h>

// PIQuantumDQN: 4-qubit, 5-layer re-uploading circuit, B=524288 samples.
// R13: fix register-pressure spills. R12's layer-0 kron held ar..bi(32) +
// t3(32) + re/im(64) + rc/rs/ryt(24) > 150 regs against the 128-VGPR cap
// of __launch_bounds__(256,4) => scratch spills (same allocator pressure
// that put R11's state into AGPRs). Here layer 0 is a two-stage fused kron:
// t23 = q2 (x) q3 (8 regs), k01 = q0 (x) q1 (8 regs), then re/im filled
// directly => peak ~110 regs, no spill, and 24 fewer pk ops.
// Gate forms (R10): RY 3-shear (6 pk/pair), RX tangent (4 pk/pair, uniform
// cos folded into Wu via S^2). CNOTs are register renames.
// wire q (0 = MSB) <-> bit (3-q) of the flat index, so mask(q) = 8 >> q.

typedef float v2f __attribute__((ext_vector_type(2)));

__device__ __forceinline__ v2f splat(float x) { return (v2f){x, x}; }

__device__ __forceinline__ float rfl(float v) {
    return __uint_as_float(__builtin_amdgcn_readfirstlane(__float_as_uint(v)));
}

// RY via 3 shears on both planes: x-=t*y; y+=s*x; x-=t*y
template<int MASK>
__device__ __forceinline__ void apply_ry_sh(v2f (&re)[16], v2f (&im)[16],
                                            v2f t, v2f s) {
#pragma unroll
    for (int i0 = 0; i0 < 16; ++i0) {
        if (i0 & MASK) continue;
        const int i1 = i0 | MASK;
        v2f x, y;
        x = re[i0]; y = re[i1];
        x = x - t * y; y = y + s * x; x = x - t * y;
        re[i0] = x; re[i1] = y;
        x = im[i0]; y = im[i1];
        x = x - t * y; y = y + s * x; x = x - t * y;
        im[i0] = x; im[i1] = y;
    }
}

// RX tangent form; true output = cos(w/2) * (this output), folded into Wu.
template<int MASK>
__device__ __forceinline__ void apply_rx_t(v2f (&re)[16], v2f (&im)[16], v2f t) {
#pragma unroll
    for (int i0 = 0; i0 < 16; ++i0) {
        if (i0 & MASK) continue;
        const int i1 = i0 | MASK;
        v2f r0 = re[i0], r1 = re[i1];
        v2f m0 = im[i0], m1 = im[i1];
        re[i0] = t * m1 + r0;
        im[i0] = m0 - t * r1;
        re[i1] = t * m0 + r1;
        im[i1] = m1 - t * r0;
    }
}

template<int CMASK, int TMASK>
__device__ __forceinline__ void apply_cnot(v2f (&re)[16], v2f (&im)[16]) {
#pragma unroll
    for (int i = 0; i < 16; ++i) {
        if ((i & CMASK) && !(i & TMASK)) {
            const int j = i | TMASK;
            v2f tr = re[i]; re[i] = re[j]; re[j] = tr;
            v2f ti = im[i]; im[i] = im[j]; im[j] = ti;
        }
    }
}

__global__ __launch_bounds__(256, 4) void qdqn_kernel(
    const float* __restrict__ x,        // (B,4) fp32
    const float* __restrict__ weights,  // (5,4) fp32
    const float* __restrict__ Wm,       // (2,4) fp32
    const float* __restrict__ bv,       // (2,)  fp32
    float4* __restrict__ out,           // (B/2,4): two float2 outputs per entry
    int Bh)                             // B/2 threads
{
    const int t = blockIdx.x * blockDim.x + threadIdx.x;
    if (t >= Bh) return;

    // ---- issue the x loads first so HBM latency overlaps the uniform trig ----
    const float4 x0 = ((const float4*)x)[2 * t + 0];
    const float4 x1 = ((const float4*)x)[2 * t + 1];

    // ---- uniforms: tan(w/2) per gate + accumulated scale S = prod cos(w/2) ----
    float tw[20];
    float cp[20];
    const float INV_4PI = 0.07957747154594767f;   // w/2 rad = w*(1/4pi) rev
#pragma unroll
    for (int k = 0; k < 20; ++k) {
        float rev = weights[k] * INV_4PI;         // uniform -> scalar load
        float c = __builtin_amdgcn_cosf(rev);
        float s = __builtin_amdgcn_sinf(rev);
        tw[k] = rfl(s * __builtin_amdgcn_rcpf(c));
        cp[k] = c;
    }
    // pairwise product tree for S (cuts the 20-deep serial mul chain to 5)
    const float S =
        (((cp[0] * cp[1]) * (cp[2] * cp[3])) * ((cp[4] * cp[5]) * (cp[6] * cp[7]))) *
        ((((cp[8] * cp[9]) * (cp[10] * cp[11])) * ((cp[12] * cp[13]) * (cp[14] * cp[15]))) *
         ((cp[16] * cp[17]) * (cp[18] * cp[19])));
    const float S2 = rfl(S) * rfl(S);             // probs scale by S^2
    float Wu[8];
#pragma unroll
    for (int k = 0; k < 8; ++k) Wu[k] = rfl(Wm[k] * S2);   // fold scale here
    const float b0u = rfl(bv[0]);
    const float b1u = rfl(bv[1]);

    // ---- pack two consecutive samples into one v2f stream ----
    // RY angle phi = xn*pi/2: rev = xn*0.25, |rev|<=0.25.
    // rc=cos(phi)>=0, rs=sin(phi), ryt=tan(phi/2)=rs/(1+rc), |ryt|<=1.
    const float inv_bounds4[4] = { 0.25f / 4.8f, 0.25f / 4.0f, 0.25f / 0.418f, 0.25f / 4.0f };
    v2f rc[4], rs[4], ryt[4];
    {
        const v2f xv[4] = {
            (v2f){x0.x, x1.x}, (v2f){x0.y, x1.y}, (v2f){x0.z, x1.z}, (v2f){x0.w, x1.w}
        };
#pragma unroll
        for (int q = 0; q < 4; ++q) {
            v2f rev = xv[q] * splat(inv_bounds4[q]);
            float ra = fminf(fmaxf(rev.x, -0.25f), 0.25f);
            float rb = fminf(fmaxf(rev.y, -0.25f), 0.25f);
            float sa = __builtin_amdgcn_sinf(ra), ca = __builtin_amdgcn_cosf(ra);
            float sb = __builtin_amdgcn_sinf(rb), cb = __builtin_amdgcn_cosf(rb);
            rs[q] = (v2f){ sa, sb };
            rc[q] = (v2f){ ca, cb };
            ryt[q] = (v2f){ sa * __builtin_amdgcn_rcpf(1.0f + ca),
                            sb * __builtin_amdgcn_rcpf(1.0f + cb) };
        }
    }

    // ---- layer 0 (separable until first CNOT), RX part in tangent form ----
    // (1/cw)*RX(w)RY(a)|0> = (alpha,beta): alpha=(ca,-t*sa), beta=(sa,-t*ca)
    // Two-stage kron keeps peak pressure low: t23 = q2(x)q3, k01 = q0(x)q1,
    // then amp[(j<<2)|i] = k01[j]*t23[i].
    v2f re[16], im[16];
    {
        v2f t23r[4], t23i[4];
        {
            v2f n2 = splat(-tw[2]), n3 = splat(-tw[3]);
            v2f a2r = rc[2], a2i = n2 * rs[2], b2r = rs[2], b2i = n2 * rc[2];
            v2f a3r = rc[3], a3i = n3 * rs[3], b3r = rs[3], b3i = n3 * rc[3];
#pragma unroll
            for (int j = 0; j < 4; ++j) {
                v2f xr = (j & 2) ? b2r : a2r, xi = (j & 2) ? b2i : a2i;
                v2f yr = (j & 1) ? b3r : a3r, yi = (j & 1) ? b3i : a3i;
                t23r[j] = xr * yr - xi * yi;
                t23i[j] = xr * yi + xi * yr;
            }
        }
        v2f k01r[4], k01i[4];
        {
            v2f n0 = splat(-tw[0]), n1 = splat(-tw[1]);
            v2f a0r = rc[0], a0i = n0 * rs[0], b0r = rs[0], b0i = n0 * rc[0];
            v2f a1r = rc[1], a1i = n1 * rs[1], b1r = rs[1], b1i = n1 * rc[1];
#pragma unroll
            for (int j = 0; j < 4; ++j) {
                v2f xr = (j & 2) ? b0r : a0r, xi = (j & 2) ? b0i : a0i;
                v2f yr = (j & 1) ? b1r : a1r, yi = (j & 1) ? b1i : a1i;
                k01r[j] = xr * yr - xi * yi;
                k01i[j] = xr * yi + xi * yr;
            }
        }
#pragma unroll
        for (int j = 0; j < 4; ++j) {
#pragma unroll
            for (int i = 0; i < 4; ++i) {
                re[(j << 2) | i] = k01r[j] * t23r[i] - k01i[j] * t23i[i];
                im[(j << 2) | i] = k01r[j] * t23i[i] + k01i[j] * t23r[i];
            }
        }
    }
    apply_cnot<8, 4>(re, im);
    apply_cnot<4, 2>(re, im);
    apply_cnot<2, 1>(re, im);
    apply_cnot<1, 8>(re, im);

    // ---- layers 1..4: shear RY (6/pair), tangent RX (4/pair), free CNOTs ----
#pragma unroll
    for (int l = 1; l < 5; ++l) {
        apply_ry_sh<8>(re, im, ryt[0], rs[0]);
        apply_ry_sh<4>(re, im, ryt[1], rs[1]);
        apply_ry_sh<2>(re, im, ryt[2], rs[2]);
        apply_ry_sh<1>(re, im, ryt[3], rs[3]);
        apply_rx_t<8>(re, im, splat(tw[l * 4 + 0]));
        apply_rx_t<4>(re, im, splat(tw[l * 4 + 1]));
        apply_rx_t<2>(re, im, splat(tw[l * 4 + 2]));
        apply_rx_t<1>(re, im, splat(tw[l * 4 + 3]));
        apply_cnot<8, 4>(re, im);
        apply_cnot<4, 2>(re, im);
        apply_cnot<2, 1>(re, im);
        apply_cnot<1, 8>(re, im);
    }

    // ---- probs -> <Z_q> sign tree -> linear layer (scale folded in Wu) ----
    v2f p[16];
#pragma unroll
    for (int i = 0; i < 16; ++i) p[i] = re[i] * re[i] + im[i] * im[i];
    v2f tt[8];
#pragma unroll
    for (int i = 0; i < 8; ++i) tt[i] = p[2 * i] + p[2 * i + 1];
    v2f u[4];
#pragma unroll
    for (int i = 0; i < 4; ++i) u[i] = tt[2 * i] + tt[2 * i + 1];
    const v2f z0 = (u[0] + u[1]) - (u[2] + u[3]);           // wire 0 (bit 3)
    const v2f z1 = (u[0] - u[1]) + (u[2] - u[3]);           // wire 1 (bit 2)
    const v2f z2 = (tt[0] - tt[1]) + (tt[2] - tt[3])
                 + (tt[4] - tt[5]) + (tt[6] - tt[7]);       // wire 2 (bit 1)
    const v2f z3 = ((p[0] - p[1]) + (p[2] - p[3]))
                 + ((p[4] - p[5]) + (p[6] - p[7]))
                 + ((p[8] - p[9]) + (p[10] - p[11]))
                 + ((p[12] - p[13]) + (p[14] - p[15]));     // wire 3 (bit 0)

    v2f o0 = splat(b0u), o1 = splat(b1u);
    o0 = splat(Wu[0]) * z0 + o0; o0 = splat(Wu[1]) * z1 + o0;
    o0 = splat(Wu[2]) * z2 + o0; o0 = splat(Wu[3]) * z3 + o0;
    o1 = splat(Wu[4]) * z0 + o1; o1 = splat(Wu[5]) * z1 + o1;
    o1 = splat(Wu[6]) * z2 + o1; o1 = splat(Wu[7]) * z3 + o1;

    out[t] = make_float4(o0.x, o1.x, o0.y, o1.y);
}

extern "C" void kernel_launch(void* const* d_in, const int* in_sizes, int n_in,
                              void* d_out, int out_size, void* d_ws, size_t ws_size,
                              hipStream_t stream) {
    const float* x  = (const float*)d_in[0];
    const float* w  = (const float*)d_in[1];
    const float* Wm = (const float*)d_in[2];
    const float* bv = (const float*)d_in[3];
    float4* out = (float4*)d_out;

    const int B  = in_sizes[0] / 4;
    const int Bh = B / 2;                       // B divisible by 2 (524288)
    dim3 grid((Bh + 255) / 256), block(256);
    qdqn_kernel<<<grid, block, 0, stream>>>(x, w, Wm, bv, out, Bh);
}